// Round 7
// baseline (313.410 us; speedup 1.0000x reference)
//
#include <hip/hip_runtime.h>
#include <hip/hip_bf16.h>

// MultiLoRA forward, two streaming kernels + f32 staging through a device global:
//   K1: Bx[row,r] = sum_i x[row,i]*B[a,r,i]   (MFMA, read 134 MB of x)
//   K2: out[row,o] = sum_r Bx[row,r]*A[a,o,r] (pure-VALU f32, write 134 MB)
// SCALING = 16/16 = 1.
//
// Ledger (kernel-only = dur_us - ~161 fixed harness cost):
//   R0 fused 88.5 | R1-R3 split ~123 | R4 staged-fused 105 | R5/R6 split ~91
//
// R7 = ATTRIBUTION ROUND (single variable: K2 launched 3x, kernels frozen).
// Two attributions fit ALL data so far:
//   A: K1~60, K2~31  (then K1 is the 2x-below-roofline kernel)
//   B: K1~31, K2~60  (then K2 is)
// Three rounds (R3/R4/R6) were flat while optimizing blind; buy the
// measurement. K2 is idempotent (same g_bx, same A -> same out) and its NT
// stores make marginal runs == steady-state cost. Readout:
//   K2 = (dur_R7 - dur_R6)/2,  K1 = 91 - K2.
// Pre-committed: dur~310-320 -> attack K1 next; dur~365-380 -> attack K2;
// dur~255-275 -> fixed-overhead model wrong, re-read everything.
#define RANK   16
#define IN_F   4096
#define OUT_F  4096
#define NROWS  8192

typedef __bf16 bf16x8  __attribute__((ext_vector_type(8)));
typedef float  floatx4 __attribute__((ext_vector_type(4)));

__device__ float g_bx[NROWS * RANK];   // 512 KB f32 staging, [row][r]

static __device__ __forceinline__ bf16x8 cvt8(floatx4 a, floatx4 b) {
    bf16x8 r;
    r[0] = (__bf16)a[0]; r[1] = (__bf16)a[1]; r[2] = (__bf16)a[2]; r[3] = (__bf16)a[3];
    r[4] = (__bf16)b[0]; r[5] = (__bf16)b[1]; r[6] = (__bf16)b[2]; r[7] = (__bf16)b[3];
    return r;
}

// ---- K1: Bx tile per block (16 rows), K=4096 split 8 ways across waves ----
// Frozen (R5/R6 version).
__global__ __launch_bounds__(512, 4) void
lora_bx_kernel(const float* __restrict__ x, const float* __restrict__ Bw,
               const int* __restrict__ ids)
{
    const int tile = blockIdx.x;            // 0..511
    const int row0 = tile * 16;
    const int adapter = ids[row0 >> 11];    // 16 | 2048: no batch crossing
    const int tid  = threadIdx.x;
    const int wave = tid >> 6;              // 0..7
    const int lane = tid & 63;

    __shared__ float red[8][256];

    const int m    = lane & 15;             // x row (and C col = r via lane)
    const int quad = lane >> 4;
    const int k0   = wave * 512 + quad * 8;
    const float* xp = x + (size_t)(row0 + m) * IN_F + k0;
    const float* bp = Bw + (size_t)adapter * (RANK * IN_F) + m * IN_F + k0;

    floatx4 acc = {0.f, 0.f, 0.f, 0.f};
#pragma unroll
    for (int s = 0; s < 16; ++s) {          // 16 steps of k32
        floatx4 xa = *reinterpret_cast<const floatx4*>(xp + s * 32);
        floatx4 xb = *reinterpret_cast<const floatx4*>(xp + s * 32 + 4);
        floatx4 ba = *reinterpret_cast<const floatx4*>(bp + s * 32);
        floatx4 bb = *reinterpret_cast<const floatx4*>(bp + s * 32 + 4);
        acc = __builtin_amdgcn_mfma_f32_16x16x32_bf16(
            cvt8(xa, xb), cvt8(ba, bb), acc, 0, 0, 0);
    }
    // C layout: row = quad*4 + j (x-row), col = lane&15 (= r)
#pragma unroll
    for (int j = 0; j < 4; ++j)
        red[wave][(quad * 4 + j) * 16 + m] = acc[j];
    __syncthreads();
    if (tid < 256) {                        // t = (row%16)*16 + r
        float s = ((red[0][tid] + red[1][tid]) + (red[2][tid] + red[3][tid]))
                + ((red[4][tid] + red[5][tid]) + (red[6][tid] + red[7][tid]));
        g_bx[tile * 256 + tid] = s;         // f32 (no bf16 rounding of Bx)
    }
}

// ---- K2: fill-shaped writer. out[row, c] = dot16(Bx[row,:], A[a,c,:]) ----
// Frozen (R6 version, NT stores).
__global__ __launch_bounds__(256, 4) void
lora_out_kernel(const float* __restrict__ Aw, const int* __restrict__ ids,
                float* __restrict__ out)
{
    const int b    = blockIdx.x;            // 0..1023
    const int cc   = b & 3;                 // col chunk of 1024
    const int rg   = b >> 2;                // row group of 32 (0..255)
    const int row0 = rg * 32;
    const int adapter = ids[row0 >> 11];    // 32 | 2048: no batch crossing
    const int tid  = threadIdx.x;
    const int wave = tid >> 6;              // 0..3
    const int lane = tid & 63;
    const int c0   = cc * 1024 + wave * 256 + lane * 4;  // 4 contiguous cols

    // Preload A[a][c0+j][r] for j=0..3, r=0..15 -> 16 dwordx4 (256 B/lane).
    const float* ap = Aw + ((size_t)adapter * OUT_F + c0) * RANK;
    floatx4 a[16];                          // a[j*4+q] = A[c0+j][q*4..q*4+3]
#pragma unroll
    for (int i = 0; i < 16; ++i)
        a[i] = *reinterpret_cast<const floatx4*>(ap + i * 4);

#pragma unroll 2
    for (int rr = 0; rr < 32; ++rr) {
        const int row = row0 + rr;
        const float* bp = g_bx + (size_t)row * RANK;    // uniform: broadcast
        const floatx4 b0 = *reinterpret_cast<const floatx4*>(bp);
        const floatx4 b1 = *reinterpret_cast<const floatx4*>(bp + 4);
        const floatx4 b2 = *reinterpret_cast<const floatx4*>(bp + 8);
        const floatx4 b3 = *reinterpret_cast<const floatx4*>(bp + 12);
        floatx4 ov;
#pragma unroll
        for (int j = 0; j < 4; ++j) {
            const floatx4 a0 = a[j * 4 + 0], a1 = a[j * 4 + 1];
            const floatx4 a2 = a[j * 4 + 2], a3 = a[j * 4 + 3];
            float s = a0[0] * b0[0] + a0[1] * b0[1] + a0[2] * b0[2] + a0[3] * b0[3]
                    + a1[0] * b1[0] + a1[1] * b1[1] + a1[2] * b1[2] + a1[3] * b1[3]
                    + a2[0] * b2[0] + a2[1] * b2[1] + a2[2] * b2[2] + a2[3] * b2[3]
                    + a3[0] * b3[0] + a3[1] * b3[1] + a3[2] * b3[2] + a3[3] * b3[3];
            ov[j] = s;
        }
        __builtin_nontemporal_store(
            ov, reinterpret_cast<floatx4*>(out + (size_t)row * OUT_F + c0));
    }
}

extern "C" void kernel_launch(void* const* d_in, const int* in_sizes, int n_in,
                              void* d_out, int out_size, void* d_ws, size_t ws_size,
                              hipStream_t stream) {
    const float* x   = (const float*)d_in[0]; // [4, 2048, 4096] f32
    const float* Aw  = (const float*)d_in[1]; // [8, 4096, 16]   f32
    const float* Bw  = (const float*)d_in[2]; // [8, 16, 4096]   f32
    const int*   ids = (const int*)d_in[3];   // [4] int32
    float* out = (float*)d_out;               // [4, 2048, 4096] f32

    lora_bx_kernel <<<dim3(NROWS / 16), dim3(512), 0, stream>>>(x, Bw, ids);
    // ATTRIBUTION: K2 launched 3x (idempotent). K2 = (dur_R7 - dur_R6)/2.
    lora_out_kernel<<<dim3(1024),       dim3(256), 0, stream>>>(Aw, ids, out);
    lora_out_kernel<<<dim3(1024),       dim3(256), 0, stream>>>(Aw, ids, out);
    lora_out_kernel<<<dim3(1024),       dim3(256), 0, stream>>>(Aw, ids, out);
}

// Round 8
// 248.915 us; speedup vs baseline: 1.2591x; 1.2591x over previous
//
#include <hip/hip_runtime.h>
#include <hip/hip_bf16.h>

// MultiLoRA forward, two streaming kernels + f32 staging through a device global:
//   K1: Bx[row,r] = sum_i x[row,i]*B[a,r,i]   (read 134 MB of x; LDS-staged)
//   K2: out[row,o] = sum_r Bx[row,r]*A[a,o,r] (fill-shaped writer, 134 MB out)
// SCALING = 16/16 = 1.
//
// Ledger (kernel-only = dur_us - ~161 fixed harness cost):
//   R0 fused 88.5 | R1-R3 split ~123 | R4 staged-fused 105 | R5/R6 split ~91
//   R7 attribution: K2 = (313.4-251.9)/2 = 31 us -> K1 = 60 us. Attack K1.
// K1's loads were fragment-shaped (16 rows x 16 B, 32 B-interleaved halves):
// 2-4 sector requests per line at poor bytes/request — the read-side twin of
// the K2 store problem that cost 2x (62->31). R4's staging test was
// confounded (lockstep barriers, 16-way LDS conflicts, shallow pipeline).
// This K1: global_load_lds width16 (1 KB contiguous per instruction), 16x512
// double-buffered chunks, ONE barrier per chunk, stage-ahead whose drain is
// forced before the next stage is issued, XOR-swizzled LDS (2-way only),
// per-chunk B in registers (compute phase vmem-free).
#define RANK   16
#define IN_F   4096
#define OUT_F  4096
#define NROWS  8192
#define CHUNK  512              // floats per row per chunk (2 KB/row)
#define NCH    (IN_F / CHUNK)   // 8 chunks

typedef __bf16 bf16x8  __attribute__((ext_vector_type(8)));
typedef float  floatx4 __attribute__((ext_vector_type(4)));

__device__ float g_bx[NROWS * RANK];   // 512 KB f32 staging, [row][r]

static __device__ __forceinline__ bf16x8 cvt8(floatx4 a, floatx4 b) {
    bf16x8 r;
    r[0] = (__bf16)a[0]; r[1] = (__bf16)a[1]; r[2] = (__bf16)a[2]; r[3] = (__bf16)a[3];
    r[4] = (__bf16)b[0]; r[5] = (__bf16)b[1]; r[6] = (__bf16)b[2]; r[7] = (__bf16)b[3];
    return r;
}

// 64 lanes x 16 B = 1 KB contiguous global -> 1 KB linear LDS (dest uniform).
static __device__ __forceinline__ void stage16(const float* g, float* l) {
    __builtin_amdgcn_global_load_lds(
        (const __attribute__((address_space(1))) void*)g,
        (__attribute__((address_space(3))) void*)l, 16, 0, 0);
}

// ---- K1: Bx tile per block (16 rows), LDS-staged x, K chunked 8x512 -------
// Swizzle: LDS byte-in-row b holds global byte b ^ ((row&7)<<4). Applied as a
// lane permutation on the global source (XOR only touches bits 4-6 of the
// lane offset, i.e. permutes lanes within each 128 B sub-block of the 1 KB
// instruction) and as an XOR on the ds_read_b128 address. Bank check: start
// bank = 4*((2*quad)^(row&7)) -> 8 distinct 4-bank groups, 2 lanes each
// (row, row+8) = 2-way = free.
__global__ __launch_bounds__(512, 4) void
lora_bx_kernel(const float* __restrict__ x, const float* __restrict__ Bw,
               const int* __restrict__ ids)
{
    const int tile = blockIdx.x;            // 0..511
    const int row0 = tile * 16;
    const int adapter = ids[row0 >> 11];    // 16 | 2048: no batch crossing
    const int tid  = threadIdx.x;
    const int wave = tid >> 6;              // 0..7
    const int lane = tid & 63;
    const int m    = lane & 15;             // frag row (x row / B r)
    const int quad = lane >> 4;

    __shared__ float xs[2][16][CHUNK];      // 64 KB staged x, swizzled
    __shared__ float red[8][256];           // cross-wave reduce (8 KB)

    // Staging: wave w owns rows 2w, 2w+1; 2 instrs of 1 KB per row per chunk.
    const int r0 = 2 * wave, r1 = r0 + 1;
    const int so0 = (((lane * 16) ^ ((r0 & 7) << 4)) >> 2); // pre-swz lane off (floats)
    const int so1 = (((lane * 16) ^ ((r1 & 7) << 4)) >> 2);
    const float* xrow0 = x + (size_t)(row0 + r0) * IN_F;
    const float* xrow1 = x + (size_t)(row0 + r1) * IN_F;

    auto STAGE = [&](int c, int bf) {       // 4 instrs/wave/chunk
        const float* s0 = xrow0 + c * CHUNK;
        const float* s1 = xrow1 + c * CHUNK;
        stage16(s0 +       so0, &xs[bf][r0][0]);
        stage16(s0 + 256 + so0, &xs[bf][r0][256]);
        stage16(s1 +       so1, &xs[bf][r1][0]);
        stage16(s1 + 256 + so1, &xs[bf][r1][256]);
    };

    // B: wave w consumes k-local [w*64, w*64+64) of each chunk.
    const float* bp = Bw + (size_t)adapter * (RANK * IN_F) + m * IN_F
                    + wave * 64 + quad * 8;
    const int Cm = (m & 7) << 4;            // ds-read swizzle constant
    floatx4 acc = {0.f, 0.f, 0.f, 0.f};

    STAGE(0, 0);
    for (int c = 0; c < NCH; ++c) {
        const int bf = c & 1;
        // B chunk to regs; cvt forces the compiler's counted vmcnt to drain
        // stage(c)+B(c) HERE, before STAGE(c+1) is issued -> the prefetch is
        // never drained early.
        const float* bc = bp + c * CHUNK;
        floatx4 B00 = *reinterpret_cast<const floatx4*>(bc);
        floatx4 B01 = *reinterpret_cast<const floatx4*>(bc + 4);
        floatx4 B10 = *reinterpret_cast<const floatx4*>(bc + 32);
        floatx4 B11 = *reinterpret_cast<const floatx4*>(bc + 36);
        const bf16x8 bb0 = cvt8(B00, B01);  // step s=0 B-frag
        const bf16x8 bb1 = cvt8(B10, B11);  // step s=1 B-frag

        __syncthreads();                    // compute(c-1) done everywhere;
        if (c + 1 < NCH) STAGE(c + 1, bf ^ 1);  // safe to overwrite buf bf^1

        // Compute chunk c from xs[bf] (vmem-free: ds_read + cvt + MFMA only).
        const char* base = (const char*)xs + (size_t)bf * (16 * CHUNK * 4);
        const char* rowb = base + m * (CHUNK * 4);
#pragma unroll
        for (int s = 0; s < 2; ++s) {
            const int ka = wave * 256 + s * 128 + quad * 32;   // byte-in-row
            floatx4 xa = *reinterpret_cast<const floatx4*>(rowb + ((ka     ) ^ Cm));
            floatx4 xb = *reinterpret_cast<const floatx4*>(rowb + ((ka + 16) ^ Cm));
            acc = __builtin_amdgcn_mfma_f32_16x16x32_bf16(
                cvt8(xa, xb), (s == 0) ? bb0 : bb1, acc, 0, 0, 0);
        }
    }

    // C layout: row = quad*4 + j (x-row), col = m (= r). Reduce 8 waves.
#pragma unroll
    for (int j = 0; j < 4; ++j)
        red[wave][(quad * 4 + j) * 16 + m] = acc[j];
    __syncthreads();
    if (tid < 256) {                        // t = (row%16)*16 + r
        float s = ((red[0][tid] + red[1][tid]) + (red[2][tid] + red[3][tid]))
                + ((red[4][tid] + red[5][tid]) + (red[6][tid] + red[7][tid]));
        g_bx[tile * 256 + tid] = s;         // f32
    }
}

// ---- K2: fill-shaped writer (frozen, R6 version; 31 us measured) ----------
__global__ __launch_bounds__(256, 4) void
lora_out_kernel(const float* __restrict__ Aw, const int* __restrict__ ids,
                float* __restrict__ out)
{
    const int b    = blockIdx.x;            // 0..1023
    const int cc   = b & 3;                 // col chunk of 1024
    const int rg   = b >> 2;                // row group of 32 (0..255)
    const int row0 = rg * 32;
    const int adapter = ids[row0 >> 11];    // 32 | 2048: no batch crossing
    const int tid  = threadIdx.x;
    const int wave = tid >> 6;              // 0..3
    const int lane = tid & 63;
    const int c0   = cc * 1024 + wave * 256 + lane * 4;  // 4 contiguous cols

    const float* ap = Aw + ((size_t)adapter * OUT_F + c0) * RANK;
    floatx4 a[16];                          // a[j*4+q] = A[c0+j][q*4..q*4+3]
#pragma unroll
    for (int i = 0; i < 16; ++i)
        a[i] = *reinterpret_cast<const floatx4*>(ap + i * 4);

#pragma unroll 2
    for (int rr = 0; rr < 32; ++rr) {
        const int row = row0 + rr;
        const float* bp = g_bx + (size_t)row * RANK;    // uniform: broadcast
        const floatx4 b0 = *reinterpret_cast<const floatx4*>(bp);
        const floatx4 b1 = *reinterpret_cast<const floatx4*>(bp + 4);
        const floatx4 b2 = *reinterpret_cast<const floatx4*>(bp + 8);
        const floatx4 b3 = *reinterpret_cast<const floatx4*>(bp + 12);
        floatx4 ov;
#pragma unroll
        for (int j = 0; j < 4; ++j) {
            const floatx4 a0 = a[j * 4 + 0], a1 = a[j * 4 + 1];
            const floatx4 a2 = a[j * 4 + 2], a3 = a[j * 4 + 3];
            float s = a0[0] * b0[0] + a0[1] * b0[1] + a0[2] * b0[2] + a0[3] * b0[3]
                    + a1[0] * b1[0] + a1[1] * b1[1] + a1[2] * b1[2] + a1[3] * b1[3]
                    + a2[0] * b2[0] + a2[1] * b2[1] + a2[2] * b2[2] + a2[3] * b2[3]
                    + a3[0] * b3[0] + a3[1] * b3[1] + a3[2] * b3[2] + a3[3] * b3[3];
            ov[j] = s;
        }
        __builtin_nontemporal_store(
            ov, reinterpret_cast<floatx4*>(out + (size_t)row * OUT_F + c0));
    }
}

extern "C" void kernel_launch(void* const* d_in, const int* in_sizes, int n_in,
                              void* d_out, int out_size, void* d_ws, size_t ws_size,
                              hipStream_t stream) {
    const float* x   = (const float*)d_in[0]; // [4, 2048, 4096] f32
    const float* Aw  = (const float*)d_in[1]; // [8, 4096, 16]   f32
    const float* Bw  = (const float*)d_in[2]; // [8, 16, 4096]   f32
    const int*   ids = (const int*)d_in[3];   // [4] int32
    float* out = (float*)d_out;               // [4, 2048, 4096] f32

    lora_bx_kernel <<<dim3(NROWS / 16), dim3(512), 0, stream>>>(x, Bw, ids);
    lora_out_kernel<<<dim3(1024),       dim3(256), 0, stream>>>(Aw, ids, out);
}